// Round 13
// baseline (508.175 us; speedup 1.0000x reference)
//
#include <hip/hip_runtime.h>

typedef unsigned short u16;
typedef unsigned int u32;
typedef float f32x4 __attribute__((ext_vector_type(4)));
typedef short bfx8 __attribute__((ext_vector_type(8)));   // 8 bf16 held as shorts
typedef u16 u16x8 __attribute__((ext_vector_type(8)));
typedef u16 u16x4 __attribute__((ext_vector_type(4)));

#define MFMA_BF16(a,b,c) __builtin_amdgcn_mfma_f32_16x16x32_bf16((a),(b),(c),0,0,0)
#define GL16(src, dst) __builtin_amdgcn_global_load_lds( \
    (const __attribute__((address_space(1))) u32*)(src), \
    (__attribute__((address_space(3))) u32*)(dst), 16, 0, 0)

__device__ __forceinline__ u16 f2bf(float f) {
  unsigned u = __float_as_uint(f);
  u += 0x7fffu + ((u >> 16) & 1u);          // round to nearest even
  return (u16)(u >> 16);
}
__device__ __forceinline__ float bf2f(u16 h) {
  return __uint_as_float((unsigned)h << 16);
}

// XCD-chunked block remap (T1): requires nwg % 8 == 0 (bijective).
__device__ __forceinline__ void xcd_remap(int& bx, int& by) {
  int gx = gridDim.x, nwg = gx * gridDim.y;
  int id = by * gx + bx;
  int swz = (id & 7) * (nwg >> 3) + (id >> 3);
  bx = swz % gx; by = swz / gx;
}

#define SCALE_ATTN 0.07216878364870323f    // 192^-0.5
#define LOG2E 1.4426950408889634f          // folded into q-side scales (exp2 softmax)

// ---------------------------------------------------------------------------
// Weight transpose: in (K x N) f32 row-major -> out (N x K) bf16 row-major
// ---------------------------------------------------------------------------
__global__ __launch_bounds__(256) void wtrans_kernel(
    const float* __restrict__ in, u16* __restrict__ out, int K, int N)
{
  __shared__ float tile[32][33];
  int n0 = blockIdx.x * 32, k0 = blockIdx.y * 32;
  int tx = threadIdx.x, ty = threadIdx.y;   // block (32,8)
#pragma unroll
  for (int j = 0; j < 32; j += 8)
    tile[ty + j][tx] = in[(size_t)(k0 + ty + j) * N + n0 + tx];
  __syncthreads();
#pragma unroll
  for (int j = 0; j < 32; j += 8)
    out[(size_t)(n0 + ty + j) * K + k0 + tx] = f2bf(tile[tx][ty + j]);
}

// ---------------------------------------------------------------------------
// Gather anchors (192 threads, 3 waves all active)
// ---------------------------------------------------------------------------
__global__ __launch_bounds__(192) void gather_kernel(
    const float* __restrict__ v0, const float* __restrict__ c0,
    const float* __restrict__ v1, const float* __restrict__ c1,
    u16* __restrict__ av, u16* __restrict__ ac)
{
  int t = blockIdx.x;
  int b = t >> 11, n = t & 2047, s = n >> 10, a = n & 1023, rr = a >> 5, cc = a & 31;
  size_t pix = ((size_t)b * 128 + (1 + 4 * rr)) * 128 + (1 + 4 * cc);
  const float4* vs = (const float4*)((s ? v1 : v0) + pix * 768);
  const float4* cs = (const float4*)((s ? c1 : c0) + pix * 128);
  int tid = threadIdx.x;                    // 0..191, all active on v
  {
    float4 f = vs[tid];
    u16x4 o = { f2bf(f.x), f2bf(f.y), f2bf(f.z), f2bf(f.w) };
    *(u16x4*)(av + (size_t)t * 768 + tid * 4) = o;
  }
  if (tid < 32) {
    float4 f = cs[tid];
    u16x4 o = { f2bf(f.x), f2bf(f.y), f2bf(f.z), f2bf(f.w) };
    *(u16x4*)(ac + (size_t)t * 128 + tid * 4) = o;
  }
}

// ---------------------------------------------------------------------------
// m97-structure GEMM (XCD-chunked). EPILOG 0: coords. EPILOG 2: qkv.
// ---------------------------------------------------------------------------
template<int EPILOG>
__global__ __launch_bounds__(256) void gemm128(
    const u16* __restrict__ A, const u16* __restrict__ Bt,
    int K, int lda, int ldb,
    u16* __restrict__ qp, u16* __restrict__ kp, u16* __restrict__ vT,
    float* __restrict__ outAdd, const float* __restrict__ bias)
{
  __shared__ u16 As[128 * 32];
  __shared__ u16 Bs[128 * 32];
  const int tid = threadIdx.x;
  const int wid = tid >> 6, lane = tid & 63;
  const int g = lane >> 4, q15 = lane & 15;
  const int wm = wid >> 1, wn = wid & 1;
  int bx = blockIdx.x, by = blockIdx.y;
  xcd_remap(bx, by);
  const int m0 = by * 128, n0 = bx * 128;

  const u16* ga = A + (size_t)(m0 + (tid >> 2)) * lda + (tid & 3) * 8;
  const u16* gb = Bt + (size_t)(n0 + (tid >> 2)) * ldb + (tid & 3) * 8;
  u16* lA0 = &As[tid * 8]; u16* lA1 = &As[2048 + tid * 8];
  u16* lB0 = &Bs[tid * 8]; u16* lB1 = &Bs[2048 + tid * 8];
  const size_t a64 = (size_t)64 * lda, b64 = (size_t)64 * ldb;

  const f32x4 zero = {0.f, 0.f, 0.f, 0.f};
  f32x4 acc[4][4];
#pragma unroll
  for (int i = 0; i < 4; i++)
#pragma unroll
    for (int j = 0; j < 4; j++) acc[i][j] = zero;

  for (int kk = 0; kk < K; kk += 32) {
    GL16(ga + kk, lA0);
    GL16(ga + kk + a64, lA1);
    GL16(gb + kk, lB0);
    GL16(gb + kk + b64, lB1);
    __syncthreads();
    bfx8 af[4], bf[4];
#pragma unroll
    for (int mt = 0; mt < 4; mt++)
      af[mt] = *(const bfx8*)&As[(wm * 64 + mt * 16 + q15) * 32 + g * 8];
#pragma unroll
    for (int nt = 0; nt < 4; nt++)
      bf[nt] = *(const bfx8*)&Bs[(wn * 64 + nt * 16 + q15) * 32 + g * 8];
#pragma unroll
    for (int mt = 0; mt < 4; mt++)
#pragma unroll
      for (int nt = 0; nt < 4; nt++)
        acc[mt][nt] = MFMA_BF16(af[mt], bf[nt], acc[mt][nt]);
    __syncthreads();
  }

#pragma unroll
  for (int mt = 0; mt < 4; mt++) {
#pragma unroll
    for (int nt = 0; nt < 4; nt++) {
      const int tt = m0 + wm * 64 + mt * 16 + g * 4;      // token base (+j)
      const int c = n0 + wn * 64 + nt * 16 + q15;         // output column
      f32x4 v = acc[mt][nt];
      if (EPILOG == 0) {
        // coords: c<1536 -> qc, else kc
        int isK = c >= 1536;
        int ck = isK ? c - 1536 : c;
        int hh = ck / 192, dd = ck - hh * 192;
#pragma unroll
        for (int j = 0; j < 4; j++) {
          int t = tt + j, b = t >> 11, n = t & 2047;
          size_t ro = ((size_t)(b * 8 + hh) * 2048 + n) * 384;
          u16 val = f2bf(v[j]);
          if (!isK) qp[ro + 192 + dd] = val;
          else      kp[ro + (size_t)((((24 + (dd >> 3)) ^ (n & 7)) << 3) + (dd & 7))] = val;
        }
      } else {
        // qkv: c<1536 q | <3072 k | else v
        if (c < 1536) {
          int hh = c / 192, dd = c - hh * 192;
#pragma unroll
          for (int j = 0; j < 4; j++) {
            int t = tt + j, b = t >> 11, n = t & 2047;
            size_t ro = ((size_t)(b * 8 + hh) * 2048 + n) * 384;
            qp[ro + dd] = f2bf(v[j]);
          }
        } else if (c < 3072) {
          int ck = c - 1536;
          int hh = ck / 192, dd = ck - hh * 192;
          int chunk = dd >> 3, e = dd & 7;
#pragma unroll
          for (int j = 0; j < 4; j++) {
            int t = tt + j, b = t >> 11, n = t & 2047;
            size_t ro = ((size_t)(b * 8 + hh) * 2048 + n) * 384;
            kp[ro + (size_t)(((chunk ^ (n & 7)) << 3) + e)] = f2bf(v[j]);
          }
        } else {
          int cv = c - 3072;
          int hh = cv / 192, dv = cv - hh * 192;
          int t0 = tt, b = t0 >> 11, n = t0 & 2047;
          u16x4 o = { f2bf(v[0]), f2bf(v[1]), f2bf(v[2]), f2bf(v[3]) };
          *(u16x4*)(vT + ((size_t)(b * 8 + hh) * 192 + dv) * 2048 + n) = o;
        }
      }
    }
  }
}

// ---------------------------------------------------------------------------
// Out-proj GEMM, 64x128 tile (768 blocks, 3/CU) -- confirmed -14 us.
// ---------------------------------------------------------------------------
__global__ __launch_bounds__(256) void gemm_out64(
    const u16* __restrict__ A, const u16* __restrict__ Bt,
    float* __restrict__ outAdd, const float* __restrict__ bias)
{
  __shared__ u16 As[64 * 32];
  __shared__ u16 Bs[128 * 32];
  const int K = 1536;
  const int tid = threadIdx.x;
  const int wid = tid >> 6, lane = tid & 63;
  const int g = lane >> 4, q15 = lane & 15;
  const int wm = wid >> 1, wn = wid & 1;
  int bx = blockIdx.x, by = blockIdx.y;
  xcd_remap(bx, by);
  const int m0 = by * 64, n0 = bx * 128;

  const u16* ga = A + (size_t)(m0 + (tid >> 2)) * K + (tid & 3) * 8;
  const u16* gb = Bt + (size_t)(n0 + (tid >> 2)) * K + (tid & 3) * 8;
  u16* lA0 = &As[tid * 8];
  u16* lB0 = &Bs[tid * 8]; u16* lB1 = &Bs[2048 + tid * 8];
  const size_t b64 = (size_t)64 * K;

  const f32x4 zero = {0.f, 0.f, 0.f, 0.f};
  f32x4 acc[2][4];
#pragma unroll
  for (int i = 0; i < 2; i++)
#pragma unroll
    for (int j = 0; j < 4; j++) acc[i][j] = zero;

  for (int kk = 0; kk < K; kk += 32) {
    GL16(ga + kk, lA0);
    GL16(gb + kk, lB0);
    GL16(gb + kk + b64, lB1);
    __syncthreads();
    bfx8 af[2], bf[4];
#pragma unroll
    for (int mt = 0; mt < 2; mt++)
      af[mt] = *(const bfx8*)&As[(wm * 32 + mt * 16 + q15) * 32 + g * 8];
#pragma unroll
    for (int nt = 0; nt < 4; nt++)
      bf[nt] = *(const bfx8*)&Bs[(wn * 64 + nt * 16 + q15) * 32 + g * 8];
#pragma unroll
    for (int mt = 0; mt < 2; mt++)
#pragma unroll
      for (int nt = 0; nt < 4; nt++)
        acc[mt][nt] = MFMA_BF16(af[mt], bf[nt], acc[mt][nt]);
    __syncthreads();
  }

#pragma unroll
  for (int mt = 0; mt < 2; mt++) {
#pragma unroll
    for (int nt = 0; nt < 4; nt++) {
      const int tt = m0 + wm * 32 + mt * 16 + g * 4;
      const int c = n0 + wn * 64 + nt * 16 + q15;
      f32x4 v = acc[mt][nt];
      float bb = bias[c];
#pragma unroll
      for (int j = 0; j < 4; j++) {
        int t = tt + j, b = t >> 11, n = t & 2047;
        int s = n >> 10, a = n & 1023, rr = a >> 5, cc2 = a & 31;
        size_t orow = (size_t)(s * 4 + b) * 16384 + (size_t)(1 + 4 * rr) * 128 + (1 + 4 * cc2);
        outAdd[orow * 768 + c] += v[j] + bb;
      }
    }
  }
}

// ---------------------------------------------------------------------------
// Fused RMSNorm (192-thread blocks). Q-side scales carry LOG2E so attention
// logits come out in base-2 units (attn uses raw exp2 -- one fewer v_mul per
// exponential). K-side scales unchanged (LOG2E applied exactly once via q).
// ---------------------------------------------------------------------------
__global__ __launch_bounds__(192) void rms_all_kernel(
    u16* __restrict__ qpack, u16* __restrict__ kpack,
    const float* __restrict__ qnw, const float* __restrict__ knw,
    const float* __restrict__ cnw, const float* __restrict__ relw)
{
  __shared__ float red[3][3];
  int t = blockIdx.x, tid = threadIdx.x;   // tid 0..191, all active
  int b = t >> 11, n = t & 2047;
  float sqv = 0.f, skv = 0.f, sc = 0.f;
  u16x8 uqv, ukv, uqc, ukc;
  int h = tid / 24, c = tid % 24;
  size_t ro = ((size_t)(b * 8 + h) * 2048 + n) * 384;
  uqv = *(const u16x8*)(qpack + ro + c * 8);
  ukv = *(const u16x8*)(kpack + ro + ((c ^ (n & 7)) * 8));
  uqc = *(const u16x8*)(qpack + ro + 192 + c * 8);
  ukc = *(const u16x8*)(kpack + ro + (((24 + c) ^ (n & 7)) * 8));
#pragma unroll
  for (int e = 0; e < 8; e++) {
    float a = bf2f(uqv[e]); sqv += a * a;
    float d = bf2f(ukv[e]); skv += d * d;
    float x = bf2f(uqc[e]); sc += x * x;
    float y = bf2f(ukc[e]); sc += y * y;
  }
#pragma unroll
  for (int o = 32; o >= 1; o >>= 1) {
    sqv += __shfl_xor(sqv, o); skv += __shfl_xor(skv, o); sc += __shfl_xor(sc, o);
  }
  int wv = tid >> 6;
  if ((tid & 63) == 0) { red[0][wv] = sqv; red[1][wv] = skv; red[2][wv] = sc; }
  __syncthreads();
  sqv = red[0][0] + red[0][1] + red[0][2];
  skv = red[1][0] + red[1][1] + red[1][2];
  sc  = red[2][0] + red[2][1] + red[2][2];
  float fqv = rsqrtf(sqv * (1.f / 1536.f) + 1e-6f) * (SCALE_ATTN * LOG2E);
  float fkv = rsqrtf(skv * (1.f / 1536.f) + 1e-6f);
  float fc  = rsqrtf(sc * (1.f / 3072.f) + 1e-6f);
  float fqc = fc * (SCALE_ATTN * LOG2E) * relw[0];
  u16x8 o0, o1, o2, o3;
#pragma unroll
  for (int e = 0; e < 8; e++) {
    int col = tid * 8 + e;
    o0[e] = f2bf(bf2f(uqv[e]) * fqv * qnw[col]);
    o1[e] = f2bf(bf2f(ukv[e]) * fkv * knw[col]);
    o2[e] = f2bf(bf2f(uqc[e]) * fqc * cnw[col]);
    o3[e] = f2bf(bf2f(ukc[e]) * fc  * cnw[1536 + col]);
  }
  *(u16x8*)(qpack + ro + c * 8) = o0;
  *(u16x8*)(kpack + ro + ((c ^ (n & 7)) * 8)) = o1;
  *(u16x8*)(qpack + ro + 192 + c * 8) = o2;
  *(u16x8*)(kpack + ro + (((24 + c) ^ (n & 7)) * 8)) = o3;
}

// ---------------------------------------------------------------------------
// Flash attention (round-3 proven schedule; logits arrive in base-2 units so
// the softmax uses raw exp2f -- 16 v_mul/lane-iter removed vs __expf).
//   iter t:  store slice t-1 (nt)  ->  stage K/V t+1  ->  load slice t (nt)
//            -> compute  ->  s_waitcnt vmcnt(3)  ->  raw s_barrier
// ---------------------------------------------------------------------------
__global__ __launch_bounds__(256, 2) void attn_kernel(
    const u16* __restrict__ qpack, const u16* __restrict__ kpack,
    const u16* __restrict__ vT, u16* __restrict__ attnO,
    const float* __restrict__ cpy_v0, const float* __restrict__ cpy_v1,
    float* __restrict__ cpy_out)
{
  __shared__ u16 Ks[2][32 * 384];   // 24 KB each, pre-swizzled content
  __shared__ u16 Vs[2][192 * 32];   // 12 KB each, source-swizzled staging

  const int tid = threadIdx.x;
  const int wid = tid >> 6, lane = tid & 63;
  const int g = lane >> 4, q15 = lane & 15;
  const int bid = blockIdx.x;
  const int bh = (bid & 7) * 4 + ((bid >> 3) >> 4);   // XCD-chunked
  const int q0 = ((bid >> 3) & 15) * 128 + wid * 32;
  const int b = bh >> 3, h = bh & 7;
  const int sw = q15 & 7;
  const int vsw = g ^ (q15 & 3);
  const bool hi = g >= 2;
  const int srcA = q15 + ((g & 1) << 5);

  // fused-copy pointers: 512 blk x 256 thr x 64 iter x 3 = 25,165,824 f32x4
  const f32x4* cs0 = (const f32x4*)cpy_v0;
  const f32x4* cs1 = (const f32x4*)cpy_v1;
  f32x4* cdst = (f32x4*)cpy_out;
  const size_t cgid = (size_t)bid * 256 + tid;
  const size_t CHALF = 12582912ull;          // f32x4 per half
  const size_t CSLAB = 8388608ull;           // 64 iters * 131072 threads

  bfx8 qf[2][12];
  {
    const u16* qb = qpack + ((size_t)bh * 2048 + q0 + q15) * 384 + g * 8;
#pragma unroll
    for (int s = 0; s < 2; s++)
#pragma unroll
      for (int c = 0; c < 12; c++)
        qf[s][c] = *(const bfx8*)(qb + s * 16 * 384 + c * 32);
  }

  const f32x4 zero = {0.f, 0.f, 0.f, 0.f};
  f32x4 acc[2][12];
#pragma unroll
  for (int s = 0; s < 2; s++)
#pragma unroll
    for (int i = 0; i < 12; i++) acc[s][i] = zero;
  float m0 = -3e30f, m1 = -3e30f, l0 = 0.f, l1 = 0.f;

  const char* kg = (const char*)(kpack + (size_t)bh * 2048 * 384);
  const char* vg = (const char*)(vT + (size_t)bh * 192 * 2048);

  auto stage = [&](int buf, int kb) {
    const char* ks = kg + (size_t)kb * 768;
#pragma unroll
    for (int j = 0; j < 6; j++) {
      int off = j * 4096 + tid * 16;
      GL16(ks + off, (char*)&Ks[buf][0] + off);
    }
    const char* vsrc = vg + (size_t)kb * 2;
#pragma unroll
    for (int j = 0; j < 3; j++) {
      int off = j * 4096 + tid * 16;
      int row = off >> 6;
      int cc = (tid & 3) ^ (row & 3);
      GL16(vsrc + (size_t)row * 4096 + cc * 16, (char*)&Vs[buf][0] + off);
    }
  };

  stage(0, 0);
  asm volatile("s_waitcnt vmcnt(0)" ::: "memory");
  __builtin_amdgcn_s_barrier();

  int cur = 0;
  f32x4 cr0, cr1, cr2;
  for (int t = 0; t < 64; t++) {
    // 1. store slice t-1 (data loaded a full iteration ago -> wait is free)
    if (t > 0) {
      const size_t pb = (size_t)(t - 1) * 131072ull + cgid;
      __builtin_nontemporal_store(cr0, &cdst[pb]);
      __builtin_nontemporal_store(cr1, &cdst[pb + CSLAB]);
      __builtin_nontemporal_store(cr2, &cdst[pb + 2 * CSLAB]);
    }
    // 2. stage next K/V tile (9 global_load_lds)
    if (t < 63) stage(cur ^ 1, (t + 1) * 32);
    // 3. issue copy loads for slice t (3 newest vmem ops -> excluded by vmcnt(3))
    {
      const size_t i0 = (size_t)t * 131072ull + cgid;
      const size_t i1 = i0 + CSLAB, i2 = i0 + 2 * CSLAB;
      cr0 = __builtin_nontemporal_load(&cs0[i0]);                 // slab0 in v0
      cr1 = (i1 < CHALF) ? __builtin_nontemporal_load(&cs0[i1])
                         : __builtin_nontemporal_load(&cs1[i1 - CHALF]);
      cr2 = __builtin_nontemporal_load(&cs1[i2 - CHALF]);         // slab2 in v1
    }

    f32x4 s00 = zero, s01 = zero, s10 = zero, s11 = zero;
    const u16* Kc = &Ks[cur][0];
    __builtin_amdgcn_s_setprio(1);
#pragma unroll
    for (int c = 0; c < 12; c++) {
      int ch = ((((c << 2) + g) ^ sw) << 3);
      bfx8 k0 = *(const bfx8*)(Kc + q15 * 384 + ch);
      bfx8 k1 = *(const bfx8*)(Kc + (q15 + 16) * 384 + ch);
      s00 = MFMA_BF16(k0, qf[0][c], s00);
      s01 = MFMA_BF16(k0, qf[1][c], s01);
      s10 = MFMA_BF16(k1, qf[0][c], s10);
      s11 = MFMA_BF16(k1, qf[1][c], s11);
    }
    __builtin_amdgcn_s_setprio(0);

    // per-lane partial max only; full cross-lane reduce deferred into the
    // rarely-taken rescale branch (__any over partials == __any over max)
    float bm0 = fmaxf(fmaxf(fmaxf(s00[0], s00[1]), fmaxf(s00[2], s00[3])),
                      fmaxf(fmaxf(s10[0], s10[1]), fmaxf(s10[2], s10[3])));
    float bm1 = fmaxf(fmaxf(fmaxf(s01[0], s01[1]), fmaxf(s01[2], s01[3])),
                      fmaxf(fmaxf(s11[0], s11[1]), fmaxf(s11[2], s11[3])));

    if (__any((bm0 > m0 + 11.5f) | (bm1 > m1 + 11.5f))) {   // defer-max, base-2
      bm0 = fmaxf(bm0, __shfl_xor(bm0, 16)); bm0 = fmaxf(bm0, __shfl_xor(bm0, 32));
      bm1 = fmaxf(bm1, __shfl_xor(bm1, 16)); bm1 = fmaxf(bm1, __shfl_xor(bm1, 32));
      float n0 = fmaxf(m0, bm0), n1 = fmaxf(m1, bm1);
      float c0 = exp2f(m0 - n0), c1 = exp2f(m1 - n1);
      l0 *= c0; l1 *= c1;
#pragma unroll
      for (int i = 0; i < 12; i++) {
#pragma unroll
        for (int j = 0; j < 4; j++) { acc[0][i][j] *= c0; acc[1][i][j] *= c1; }
      }
      m0 = n0; m1 = n1;
    }

    float p0[8], p1[8];
    float rs0 = 0.f, rs1 = 0.f;
#pragma unroll
    for (int j = 0; j < 4; j++) {
      p0[j]     = exp2f(s00[j] - m0);
      p0[4 + j] = exp2f(s10[j] - m0);
      p1[j]     = exp2f(s01[j] - m1);
      p1[4 + j] = exp2f(s11[j] - m1);
      rs0 += p0[j] + p0[4 + j];
      rs1 += p1[j] + p1[4 + j];
    }
    // per-lane partial l; cross-lane reduce deferred to after the loop
    l0 += rs0; l1 += rs1;

    union { bfx8 v; u32 w[4]; } pt0, pt1;
    {
      u32 w0 = (u32)f2bf(p0[0]) | ((u32)f2bf(p0[1]) << 16);
      u32 w1 = (u32)f2bf(p0[2]) | ((u32)f2bf(p0[3]) << 16);
      u32 w2 = (u32)f2bf(p0[4]) | ((u32)f2bf(p0[5]) << 16);
      u32 w3 = (u32)f2bf(p0[6]) | ((u32)f2bf(p0[7]) << 16);
      u32 a0 = __shfl((int)w0, srcA),      b0 = __shfl((int)w2, srcA);
      u32 a1 = __shfl((int)w1, srcA),      b1 = __shfl((int)w3, srcA);
      u32 a2 = __shfl((int)w0, srcA + 16), b2 = __shfl((int)w2, srcA + 16);
      u32 a3 = __shfl((int)w1, srcA + 16), b3 = __shfl((int)w3, srcA + 16);
      pt0.w[0] = hi ? b0 : a0; pt0.w[1] = hi ? b1 : a1;
      pt0.w[2] = hi ? b2 : a2; pt0.w[3] = hi ? b3 : a3;
    }
    {
      u32 w0 = (u32)f2bf(p1[0]) | ((u32)f2bf(p1[1]) << 16);
      u32 w1 = (u32)f2bf(p1[2]) | ((u32)f2bf(p1[3]) << 16);
      u32 w2 = (u32)f2bf(p1[4]) | ((u32)f2bf(p1[5]) << 16);
      u32 w3 = (u32)f2bf(p1[6]) | ((u32)f2bf(p1[7]) << 16);
      u32 a0 = __shfl((int)w0, srcA),      b0 = __shfl((int)w2, srcA);
      u32 a1 = __shfl((int)w1, srcA),      b1 = __shfl((int)w3, srcA);
      u32 a2 = __shfl((int)w0, srcA + 16), b2 = __shfl((int)w2, srcA + 16);
      u32 a3 = __shfl((int)w1, srcA + 16), b3 = __shfl((int)w3, srcA + 16);
      pt1.w[0] = hi ? b0 : a0; pt1.w[1] = hi ? b1 : a1;
      pt1.w[2] = hi ? b2 : a2; pt1.w[3] = hi ? b3 : a3;
    }

    const u16* Vc = &Vs[cur][0];
    __builtin_amdgcn_s_setprio(1);
#pragma unroll
    for (int dt = 0; dt < 12; dt++) {
      bfx8 vf = *(const bfx8*)(Vc + dt * 512 + q15 * 32 + vsw * 8);
      acc[0][dt] = MFMA_BF16(vf, pt0.v, acc[0][dt]);
      acc[1][dt] = MFMA_BF16(vf, pt1.v, acc[1][dt]);
    }
    __builtin_amdgcn_s_setprio(0);

    // drain stores+stage for barrier correctness; copy loads stay in flight
    asm volatile("s_waitcnt vmcnt(3)" ::: "memory");
    __builtin_amdgcn_s_barrier();
    cur ^= 1;
  }

  // final copy slice (compiler inserts the load wait; loads are an iter old)
  {
    const size_t pb = (size_t)63 * 131072ull + cgid;
    __builtin_nontemporal_store(cr0, &cdst[pb]);
    __builtin_nontemporal_store(cr1, &cdst[pb + CSLAB]);
    __builtin_nontemporal_store(cr2, &cdst[pb + 2 * CSLAB]);
  }

  // deferred cross-lane l reduction
  l0 += __shfl_xor(l0, 16); l0 += __shfl_xor(l0, 32);
  l1 += __shfl_xor(l1, 16); l1 += __shfl_xor(l1, 32);

  float li0 = 1.f / l0, li1 = 1.f / l1;
  u16* ob = attnO + ((size_t)(b * 2048 + q0 + q15)) * 1536 + h * 192;
#pragma unroll
  for (int dt = 0; dt < 12; dt++) {
    u16x4 o0, o1;
#pragma unroll
    for (int j = 0; j < 4; j++) {
      o0[j] = f2bf(acc[0][dt][j] * li0);
      o1[j] = f2bf(acc[1][dt][j] * li1);
    }
    *(u16x4*)(ob + dt * 16 + g * 4) = o0;
    *(u16x4*)(ob + (size_t)16 * 1536 + dt * 16 + g * 4) = o1;
  }
}

// ---------------------------------------------------------------------------
extern "C" void kernel_launch(void* const* d_in, const int* in_sizes, int n_in,
                              void* d_out, int out_size, void* d_ws, size_t ws_size,
                              hipStream_t stream)
{
  const float* values0 = (const float*)d_in[0];
  const float* coords0 = (const float*)d_in[1];
  const float* values1 = (const float*)d_in[2];
  const float* coords1 = (const float*)d_in[3];
  const float* w_qkv   = (const float*)d_in[4];
  const float* qnorm_w = (const float*)d_in[5];
  const float* knorm_w = (const float*)d_in[6];
  const float* w_coords= (const float*)d_in[7];
  const float* cnorm_w = (const float*)d_in[8];
  const float* relw    = (const float*)d_in[9];
  const float* out_w   = (const float*)d_in[10];
  const float* out_b   = (const float*)d_in[11];
  float* out = (float*)d_out;
  (void)in_sizes; (void)n_in; (void)out_size; (void)ws_size;

  char* ws = (char*)d_ws;
  u16* qpack   = (u16*)(ws);                      // 50,331,648 B
  u16* kpack   = (u16*)(ws + 50331648ull);        // 50,331,648 B
  u16* vT      = (u16*)(ws + 100663296ull);       // 25,165,824 B
  u16* attnO   = (u16*)(ws + 125829120ull);       // 25,165,824 B
  u16* av      = (u16*)(ws + 150994944ull);       // 12,582,912 B
  u16* ac      = (u16*)(ws + 163577856ull);       //  2,097,152 B
  u16* wqkvT   = (u16*)(ws + 165675008ull);       //  7,077,888 B
  u16* wcoordT = (u16*)(ws + 172752896ull);       //    786,432 B
  u16* outwT   = (u16*)(ws + 173539328ull);       //  2,359,296 B

  wtrans_kernel<<<dim3(144, 24), dim3(32, 8), 0, stream>>>(w_qkv, wqkvT, 768, 4608);
  wtrans_kernel<<<dim3(96, 4),   dim3(32, 8), 0, stream>>>(w_coords, wcoordT, 128, 3072);
  wtrans_kernel<<<dim3(24, 48),  dim3(32, 8), 0, stream>>>(out_w, outwT, 1536, 768);
  gather_kernel<<<8192, 192, 0, stream>>>(values0, coords0, values1, coords1, av, ac);

  // qkv = av @ w_qkv : M=8192 N=4608 K=768, scatter into qpack/kpack/vT
  gemm128<2><<<dim3(36, 64), 256, 0, stream>>>(av, wqkvT, 768, 768, 768,
                                               qpack, kpack, vT, nullptr, nullptr);
  // coords = ac @ w_coords : M=8192 N=3072 K=128, scatter into coord halves
  gemm128<0><<<dim3(24, 64), 256, 0, stream>>>(ac, wcoordT, 128, 128, 128,
                                               qpack, kpack, nullptr, nullptr, nullptr);

  rms_all_kernel<<<8192, 192, 0, stream>>>(qpack, kpack, qnorm_w, knorm_w, cnorm_w, relw);

  // attention + fused values->out base copy (replaces the two hipMemcpyAsync)
  attn_kernel<<<512, 256, 0, stream>>>(qpack, kpack, vT, attnO,
                                       values0, values1, out);

  // out_proj + scatter-add: M=8192 N=768 K=1536, 64x128 tile (768 blocks)
  gemm_out64<<<dim3(6, 128), 256, 0, stream>>>(attnO, outwT, out, out_b);
}

// Round 14
// 496.457 us; speedup vs baseline: 1.0236x; 1.0236x over previous
//
#include <hip/hip_runtime.h>

typedef unsigned short u16;
typedef unsigned int u32;
typedef float f32x4 __attribute__((ext_vector_type(4)));
typedef short bfx8 __attribute__((ext_vector_type(8)));   // 8 bf16 held as shorts
typedef u16 u16x8 __attribute__((ext_vector_type(8)));
typedef u16 u16x4 __attribute__((ext_vector_type(4)));

#define MFMA_BF16(a,b,c) __builtin_amdgcn_mfma_f32_16x16x32_bf16((a),(b),(c),0,0,0)
#define GL16(src, dst) __builtin_amdgcn_global_load_lds( \
    (const __attribute__((address_space(1))) u32*)(src), \
    (__attribute__((address_space(3))) u32*)(dst), 16, 0, 0)
#define EXP2R(x) __builtin_amdgcn_exp2f(x)   // bare v_exp_f32 (no libm wrapper)

__device__ __forceinline__ u16 f2bf(float f) {
  unsigned u = __float_as_uint(f);
  u += 0x7fffu + ((u >> 16) & 1u);          // round to nearest even
  return (u16)(u >> 16);
}
__device__ __forceinline__ float bf2f(u16 h) {
  return __uint_as_float((unsigned)h << 16);
}

// XCD-chunked block remap (T1): requires nwg % 8 == 0 (bijective).
__device__ __forceinline__ void xcd_remap(int& bx, int& by) {
  int gx = gridDim.x, nwg = gx * gridDim.y;
  int id = by * gx + bx;
  int swz = (id & 7) * (nwg >> 3) + (id >> 3);
  bx = swz % gx; by = swz / gx;
}

#define SCALE_ATTN 0.07216878364870323f    // 192^-0.5
#define LOG2E 1.4426950408889634f          // folded into q-side scales (exp2 softmax)

// ---------------------------------------------------------------------------
// Weight transpose: in (K x N) f32 row-major -> out (N x K) bf16 row-major
// ---------------------------------------------------------------------------
__global__ __launch_bounds__(256) void wtrans_kernel(
    const float* __restrict__ in, u16* __restrict__ out, int K, int N)
{
  __shared__ float tile[32][33];
  int n0 = blockIdx.x * 32, k0 = blockIdx.y * 32;
  int tx = threadIdx.x, ty = threadIdx.y;   // block (32,8)
#pragma unroll
  for (int j = 0; j < 32; j += 8)
    tile[ty + j][tx] = in[(size_t)(k0 + ty + j) * N + n0 + tx];
  __syncthreads();
#pragma unroll
  for (int j = 0; j < 32; j += 8)
    out[(size_t)(n0 + ty + j) * K + k0 + tx] = f2bf(tile[tx][ty + j]);
}

// ---------------------------------------------------------------------------
// Gather anchors (192 threads, 3 waves all active)
// ---------------------------------------------------------------------------
__global__ __launch_bounds__(192) void gather_kernel(
    const float* __restrict__ v0, const float* __restrict__ c0,
    const float* __restrict__ v1, const float* __restrict__ c1,
    u16* __restrict__ av, u16* __restrict__ ac)
{
  int t = blockIdx.x;
  int b = t >> 11, n = t & 2047, s = n >> 10, a = n & 1023, rr = a >> 5, cc = a & 31;
  size_t pix = ((size_t)b * 128 + (1 + 4 * rr)) * 128 + (1 + 4 * cc);
  const float4* vs = (const float4*)((s ? v1 : v0) + pix * 768);
  const float4* cs = (const float4*)((s ? c1 : c0) + pix * 128);
  int tid = threadIdx.x;                    // 0..191, all active on v
  {
    float4 f = vs[tid];
    u16x4 o = { f2bf(f.x), f2bf(f.y), f2bf(f.z), f2bf(f.w) };
    *(u16x4*)(av + (size_t)t * 768 + tid * 4) = o;
  }
  if (tid < 32) {
    float4 f = cs[tid];
    u16x4 o = { f2bf(f.x), f2bf(f.y), f2bf(f.z), f2bf(f.w) };
    *(u16x4*)(ac + (size_t)t * 128 + tid * 4) = o;
  }
}

// ---------------------------------------------------------------------------
// m97-structure GEMM (XCD-chunked). EPILOG 0: coords. EPILOG 2: qkv.
// ---------------------------------------------------------------------------
template<int EPILOG>
__global__ __launch_bounds__(256) void gemm128(
    const u16* __restrict__ A, const u16* __restrict__ Bt,
    int K, int lda, int ldb,
    u16* __restrict__ qp, u16* __restrict__ kp, u16* __restrict__ vT,
    float* __restrict__ outAdd, const float* __restrict__ bias)
{
  __shared__ u16 As[128 * 32];
  __shared__ u16 Bs[128 * 32];
  const int tid = threadIdx.x;
  const int wid = tid >> 6, lane = tid & 63;
  const int g = lane >> 4, q15 = lane & 15;
  const int wm = wid >> 1, wn = wid & 1;
  int bx = blockIdx.x, by = blockIdx.y;
  xcd_remap(bx, by);
  const int m0 = by * 128, n0 = bx * 128;

  const u16* ga = A + (size_t)(m0 + (tid >> 2)) * lda + (tid & 3) * 8;
  const u16* gb = Bt + (size_t)(n0 + (tid >> 2)) * ldb + (tid & 3) * 8;
  u16* lA0 = &As[tid * 8]; u16* lA1 = &As[2048 + tid * 8];
  u16* lB0 = &Bs[tid * 8]; u16* lB1 = &Bs[2048 + tid * 8];
  const size_t a64 = (size_t)64 * lda, b64 = (size_t)64 * ldb;

  const f32x4 zero = {0.f, 0.f, 0.f, 0.f};
  f32x4 acc[4][4];
#pragma unroll
  for (int i = 0; i < 4; i++)
#pragma unroll
    for (int j = 0; j < 4; j++) acc[i][j] = zero;

  for (int kk = 0; kk < K; kk += 32) {
    GL16(ga + kk, lA0);
    GL16(ga + kk + a64, lA1);
    GL16(gb + kk, lB0);
    GL16(gb + kk + b64, lB1);
    __syncthreads();
    bfx8 af[4], bf[4];
#pragma unroll
    for (int mt = 0; mt < 4; mt++)
      af[mt] = *(const bfx8*)&As[(wm * 64 + mt * 16 + q15) * 32 + g * 8];
#pragma unroll
    for (int nt = 0; nt < 4; nt++)
      bf[nt] = *(const bfx8*)&Bs[(wn * 64 + nt * 16 + q15) * 32 + g * 8];
#pragma unroll
    for (int mt = 0; mt < 4; mt++)
#pragma unroll
      for (int nt = 0; nt < 4; nt++)
        acc[mt][nt] = MFMA_BF16(af[mt], bf[nt], acc[mt][nt]);
    __syncthreads();
  }

#pragma unroll
  for (int mt = 0; mt < 4; mt++) {
#pragma unroll
    for (int nt = 0; nt < 4; nt++) {
      const int tt = m0 + wm * 64 + mt * 16 + g * 4;      // token base (+j)
      const int c = n0 + wn * 64 + nt * 16 + q15;         // output column
      f32x4 v = acc[mt][nt];
      if (EPILOG == 0) {
        // coords: c<1536 -> qc, else kc
        int isK = c >= 1536;
        int ck = isK ? c - 1536 : c;
        int hh = ck / 192, dd = ck - hh * 192;
#pragma unroll
        for (int j = 0; j < 4; j++) {
          int t = tt + j, b = t >> 11, n = t & 2047;
          size_t ro = ((size_t)(b * 8 + hh) * 2048 + n) * 384;
          u16 val = f2bf(v[j]);
          if (!isK) qp[ro + 192 + dd] = val;
          else      kp[ro + (size_t)((((24 + (dd >> 3)) ^ (n & 7)) << 3) + (dd & 7))] = val;
        }
      } else {
        // qkv: c<1536 q | <3072 k | else v
        if (c < 1536) {
          int hh = c / 192, dd = c - hh * 192;
#pragma unroll
          for (int j = 0; j < 4; j++) {
            int t = tt + j, b = t >> 11, n = t & 2047;
            size_t ro = ((size_t)(b * 8 + hh) * 2048 + n) * 384;
            qp[ro + dd] = f2bf(v[j]);
          }
        } else if (c < 3072) {
          int ck = c - 1536;
          int hh = ck / 192, dd = ck - hh * 192;
          int chunk = dd >> 3, e = dd & 7;
#pragma unroll
          for (int j = 0; j < 4; j++) {
            int t = tt + j, b = t >> 11, n = t & 2047;
            size_t ro = ((size_t)(b * 8 + hh) * 2048 + n) * 384;
            kp[ro + (size_t)(((chunk ^ (n & 7)) << 3) + e)] = f2bf(v[j]);
          }
        } else {
          int cv = c - 3072;
          int hh = cv / 192, dv = cv - hh * 192;
          int t0 = tt, b = t0 >> 11, n = t0 & 2047;
          u16x4 o = { f2bf(v[0]), f2bf(v[1]), f2bf(v[2]), f2bf(v[3]) };
          *(u16x4*)(vT + ((size_t)(b * 8 + hh) * 192 + dv) * 2048 + n) = o;
        }
      }
    }
  }
}

// ---------------------------------------------------------------------------
// Out-proj GEMM, 64x128 tile (768 blocks, 3/CU) -- confirmed -14 us.
// ---------------------------------------------------------------------------
__global__ __launch_bounds__(256) void gemm_out64(
    const u16* __restrict__ A, const u16* __restrict__ Bt,
    float* __restrict__ outAdd, const float* __restrict__ bias)
{
  __shared__ u16 As[64 * 32];
  __shared__ u16 Bs[128 * 32];
  const int K = 1536;
  const int tid = threadIdx.x;
  const int wid = tid >> 6, lane = tid & 63;
  const int g = lane >> 4, q15 = lane & 15;
  const int wm = wid >> 1, wn = wid & 1;
  int bx = blockIdx.x, by = blockIdx.y;
  xcd_remap(bx, by);
  const int m0 = by * 64, n0 = bx * 128;

  const u16* ga = A + (size_t)(m0 + (tid >> 2)) * K + (tid & 3) * 8;
  const u16* gb = Bt + (size_t)(n0 + (tid >> 2)) * K + (tid & 3) * 8;
  u16* lA0 = &As[tid * 8];
  u16* lB0 = &Bs[tid * 8]; u16* lB1 = &Bs[2048 + tid * 8];
  const size_t b64 = (size_t)64 * K;

  const f32x4 zero = {0.f, 0.f, 0.f, 0.f};
  f32x4 acc[2][4];
#pragma unroll
  for (int i = 0; i < 2; i++)
#pragma unroll
    for (int j = 0; j < 4; j++) acc[i][j] = zero;

  for (int kk = 0; kk < K; kk += 32) {
    GL16(ga + kk, lA0);
    GL16(gb + kk, lB0);
    GL16(gb + kk + b64, lB1);
    __syncthreads();
    bfx8 af[2], bf[4];
#pragma unroll
    for (int mt = 0; mt < 2; mt++)
      af[mt] = *(const bfx8*)&As[(wm * 32 + mt * 16 + q15) * 32 + g * 8];
#pragma unroll
    for (int nt = 0; nt < 4; nt++)
      bf[nt] = *(const bfx8*)&Bs[(wn * 64 + nt * 16 + q15) * 32 + g * 8];
#pragma unroll
    for (int mt = 0; mt < 2; mt++)
#pragma unroll
      for (int nt = 0; nt < 4; nt++)
        acc[mt][nt] = MFMA_BF16(af[mt], bf[nt], acc[mt][nt]);
    __syncthreads();
  }

#pragma unroll
  for (int mt = 0; mt < 2; mt++) {
#pragma unroll
    for (int nt = 0; nt < 4; nt++) {
      const int tt = m0 + wm * 32 + mt * 16 + g * 4;
      const int c = n0 + wn * 64 + nt * 16 + q15;
      f32x4 v = acc[mt][nt];
      float bb = bias[c];
#pragma unroll
      for (int j = 0; j < 4; j++) {
        int t = tt + j, b = t >> 11, n = t & 2047;
        int s = n >> 10, a = n & 1023, rr = a >> 5, cc2 = a & 31;
        size_t orow = (size_t)(s * 4 + b) * 16384 + (size_t)(1 + 4 * rr) * 128 + (1 + 4 * cc2);
        outAdd[orow * 768 + c] += v[j] + bb;
      }
    }
  }
}

// ---------------------------------------------------------------------------
// Fused RMSNorm (192-thread blocks). Q-side scales carry LOG2E so attention
// logits come out in base-2 units.
// ---------------------------------------------------------------------------
__global__ __launch_bounds__(192) void rms_all_kernel(
    u16* __restrict__ qpack, u16* __restrict__ kpack,
    const float* __restrict__ qnw, const float* __restrict__ knw,
    const float* __restrict__ cnw, const float* __restrict__ relw)
{
  __shared__ float red[3][3];
  int t = blockIdx.x, tid = threadIdx.x;   // tid 0..191, all active
  int b = t >> 11, n = t & 2047;
  float sqv = 0.f, skv = 0.f, sc = 0.f;
  u16x8 uqv, ukv, uqc, ukc;
  int h = tid / 24, c = tid % 24;
  size_t ro = ((size_t)(b * 8 + h) * 2048 + n) * 384;
  uqv = *(const u16x8*)(qpack + ro + c * 8);
  ukv = *(const u16x8*)(kpack + ro + ((c ^ (n & 7)) * 8));
  uqc = *(const u16x8*)(qpack + ro + 192 + c * 8);
  ukc = *(const u16x8*)(kpack + ro + (((24 + c) ^ (n & 7)) * 8));
#pragma unroll
  for (int e = 0; e < 8; e++) {
    float a = bf2f(uqv[e]); sqv += a * a;
    float d = bf2f(ukv[e]); skv += d * d;
    float x = bf2f(uqc[e]); sc += x * x;
    float y = bf2f(ukc[e]); sc += y * y;
  }
#pragma unroll
  for (int o = 32; o >= 1; o >>= 1) {
    sqv += __shfl_xor(sqv, o); skv += __shfl_xor(skv, o); sc += __shfl_xor(sc, o);
  }
  int wv = tid >> 6;
  if ((tid & 63) == 0) { red[0][wv] = sqv; red[1][wv] = skv; red[2][wv] = sc; }
  __syncthreads();
  sqv = red[0][0] + red[0][1] + red[0][2];
  skv = red[1][0] + red[1][1] + red[1][2];
  sc  = red[2][0] + red[2][1] + red[2][2];
  float fqv = rsqrtf(sqv * (1.f / 1536.f) + 1e-6f) * (SCALE_ATTN * LOG2E);
  float fkv = rsqrtf(skv * (1.f / 1536.f) + 1e-6f);
  float fc  = rsqrtf(sc * (1.f / 3072.f) + 1e-6f);
  float fqc = fc * (SCALE_ATTN * LOG2E) * relw[0];
  u16x8 o0, o1, o2, o3;
#pragma unroll
  for (int e = 0; e < 8; e++) {
    int col = tid * 8 + e;
    o0[e] = f2bf(bf2f(uqv[e]) * fqv * qnw[col]);
    o1[e] = f2bf(bf2f(ukv[e]) * fkv * knw[col]);
    o2[e] = f2bf(bf2f(uqc[e]) * fqc * cnw[col]);
    o3[e] = f2bf(bf2f(ukc[e]) * fc  * cnw[1536 + col]);
  }
  *(u16x8*)(qpack + ro + c * 8) = o0;
  *(u16x8*)(kpack + ro + ((c ^ (n & 7)) * 8)) = o1;
  *(u16x8*)(qpack + ro + 192 + c * 8) = o2;
  *(u16x8*)(kpack + ro + (((24 + c) ^ (n & 7)) * 8)) = o3;
}

// ---------------------------------------------------------------------------
// Flash attention (round-3 proven schedule). Logits in base-2 units; softmax
// exponential = single v_exp_f32 via __builtin_amdgcn_exp2f (round-13's libm
// exp2f carried range-fixup VALU and regressed; this is the bare HW op).
// ---------------------------------------------------------------------------
__global__ __launch_bounds__(256, 2) void attn_kernel(
    const u16* __restrict__ qpack, const u16* __restrict__ kpack,
    const u16* __restrict__ vT, u16* __restrict__ attnO,
    const float* __restrict__ cpy_v0, const float* __restrict__ cpy_v1,
    float* __restrict__ cpy_out)
{
  __shared__ u16 Ks[2][32 * 384];   // 24 KB each, pre-swizzled content
  __shared__ u16 Vs[2][192 * 32];   // 12 KB each, source-swizzled staging

  const int tid = threadIdx.x;
  const int wid = tid >> 6, lane = tid & 63;
  const int g = lane >> 4, q15 = lane & 15;
  const int bid = blockIdx.x;
  const int bh = (bid & 7) * 4 + ((bid >> 3) >> 4);   // XCD-chunked
  const int q0 = ((bid >> 3) & 15) * 128 + wid * 32;
  const int b = bh >> 3, h = bh & 7;
  const int sw = q15 & 7;
  const int vsw = g ^ (q15 & 3);
  const bool hi = g >= 2;
  const int srcA = q15 + ((g & 1) << 5);

  // fused-copy pointers: 512 blk x 256 thr x 64 iter x 3 = 25,165,824 f32x4
  const f32x4* cs0 = (const f32x4*)cpy_v0;
  const f32x4* cs1 = (const f32x4*)cpy_v1;
  f32x4* cdst = (f32x4*)cpy_out;
  const size_t cgid = (size_t)bid * 256 + tid;
  const size_t CHALF = 12582912ull;          // f32x4 per half
  const size_t CSLAB = 8388608ull;           // 64 iters * 131072 threads

  bfx8 qf[2][12];
  {
    const u16* qb = qpack + ((size_t)bh * 2048 + q0 + q15) * 384 + g * 8;
#pragma unroll
    for (int s = 0; s < 2; s++)
#pragma unroll
      for (int c = 0; c < 12; c++)
        qf[s][c] = *(const bfx8*)(qb + s * 16 * 384 + c * 32);
  }

  const f32x4 zero = {0.f, 0.f, 0.f, 0.f};
  f32x4 acc[2][12];
#pragma unroll
  for (int s = 0; s < 2; s++)
#pragma unroll
    for (int i = 0; i < 12; i++) acc[s][i] = zero;
  float m0 = -3e30f, m1 = -3e30f, l0 = 0.f, l1 = 0.f;

  const char* kg = (const char*)(kpack + (size_t)bh * 2048 * 384);
  const char* vg = (const char*)(vT + (size_t)bh * 192 * 2048);

  auto stage = [&](int buf, int kb) {
    const char* ks = kg + (size_t)kb * 768;
#pragma unroll
    for (int j = 0; j < 6; j++) {
      int off = j * 4096 + tid * 16;
      GL16(ks + off, (char*)&Ks[buf][0] + off);
    }
    const char* vsrc = vg + (size_t)kb * 2;
#pragma unroll
    for (int j = 0; j < 3; j++) {
      int off = j * 4096 + tid * 16;
      int row = off >> 6;
      int cc = (tid & 3) ^ (row & 3);
      GL16(vsrc + (size_t)row * 4096 + cc * 16, (char*)&Vs[buf][0] + off);
    }
  };

  stage(0, 0);
  asm volatile("s_waitcnt vmcnt(0)" ::: "memory");
  __builtin_amdgcn_s_barrier();

  int cur = 0;
  f32x4 cr0, cr1, cr2;
  for (int t = 0; t < 64; t++) {
    // 1. store slice t-1 (data loaded a full iteration ago -> wait is free)
    if (t > 0) {
      const size_t pb = (size_t)(t - 1) * 131072ull + cgid;
      __builtin_nontemporal_store(cr0, &cdst[pb]);
      __builtin_nontemporal_store(cr1, &cdst[pb + CSLAB]);
      __builtin_nontemporal_store(cr2, &cdst[pb + 2 * CSLAB]);
    }
    // 2. stage next K/V tile (9 global_load_lds)
    if (t < 63) stage(cur ^ 1, (t + 1) * 32);
    // 3. issue copy loads for slice t (3 newest vmem ops -> excluded by vmcnt(3))
    {
      const size_t i0 = (size_t)t * 131072ull + cgid;
      const size_t i1 = i0 + CSLAB, i2 = i0 + 2 * CSLAB;
      cr0 = __builtin_nontemporal_load(&cs0[i0]);                 // slab0 in v0
      cr1 = (i1 < CHALF) ? __builtin_nontemporal_load(&cs0[i1])
                         : __builtin_nontemporal_load(&cs1[i1 - CHALF]);
      cr2 = __builtin_nontemporal_load(&cs1[i2 - CHALF]);         // slab2 in v1
    }

    f32x4 s00 = zero, s01 = zero, s10 = zero, s11 = zero;
    const u16* Kc = &Ks[cur][0];
    __builtin_amdgcn_s_setprio(1);
#pragma unroll
    for (int c = 0; c < 12; c++) {
      int ch = ((((c << 2) + g) ^ sw) << 3);
      bfx8 k0 = *(const bfx8*)(Kc + q15 * 384 + ch);
      bfx8 k1 = *(const bfx8*)(Kc + (q15 + 16) * 384 + ch);
      s00 = MFMA_BF16(k0, qf[0][c], s00);
      s01 = MFMA_BF16(k0, qf[1][c], s01);
      s10 = MFMA_BF16(k1, qf[0][c], s10);
      s11 = MFMA_BF16(k1, qf[1][c], s11);
    }
    __builtin_amdgcn_s_setprio(0);

    // per-lane partial max only; full cross-lane reduce deferred into the
    // rarely-taken rescale branch (__any over partials == __any over max)
    float bm0 = fmaxf(fmaxf(fmaxf(s00[0], s00[1]), fmaxf(s00[2], s00[3])),
                      fmaxf(fmaxf(s10[0], s10[1]), fmaxf(s10[2], s10[3])));
    float bm1 = fmaxf(fmaxf(fmaxf(s01[0], s01[1]), fmaxf(s01[2], s01[3])),
                      fmaxf(fmaxf(s11[0], s11[1]), fmaxf(s11[2], s11[3])));

    if (__any((bm0 > m0 + 11.5f) | (bm1 > m1 + 11.5f))) {   // defer-max, base-2
      bm0 = fmaxf(bm0, __shfl_xor(bm0, 16)); bm0 = fmaxf(bm0, __shfl_xor(bm0, 32));
      bm1 = fmaxf(bm1, __shfl_xor(bm1, 16)); bm1 = fmaxf(bm1, __shfl_xor(bm1, 32));
      float n0 = fmaxf(m0, bm0), n1 = fmaxf(m1, bm1);
      float c0 = EXP2R(m0 - n0), c1 = EXP2R(m1 - n1);
      l0 *= c0; l1 *= c1;
#pragma unroll
      for (int i = 0; i < 12; i++) {
#pragma unroll
        for (int j = 0; j < 4; j++) { acc[0][i][j] *= c0; acc[1][i][j] *= c1; }
      }
      m0 = n0; m1 = n1;
    }

    float p0[8], p1[8];
    float rs0 = 0.f, rs1 = 0.f;
#pragma unroll
    for (int j = 0; j < 4; j++) {
      p0[j]     = EXP2R(s00[j] - m0);
      p0[4 + j] = EXP2R(s10[j] - m0);
      p1[j]     = EXP2R(s01[j] - m1);
      p1[4 + j] = EXP2R(s11[j] - m1);
      rs0 += p0[j] + p0[4 + j];
      rs1 += p1[j] + p1[4 + j];
    }
    // per-lane partial l; cross-lane reduce deferred to after the loop
    l0 += rs0; l1 += rs1;

    union { bfx8 v; u32 w[4]; } pt0, pt1;
    {
      u32 w0 = (u32)f2bf(p0[0]) | ((u32)f2bf(p0[1]) << 16);
      u32 w1 = (u32)f2bf(p0[2]) | ((u32)f2bf(p0[3]) << 16);
      u32 w2 = (u32)f2bf(p0[4]) | ((u32)f2bf(p0[5]) << 16);
      u32 w3 = (u32)f2bf(p0[6]) | ((u32)f2bf(p0[7]) << 16);
      u32 a0 = __shfl((int)w0, srcA),      b0 = __shfl((int)w2, srcA);
      u32 a1 = __shfl((int)w1, srcA),      b1 = __shfl((int)w3, srcA);
      u32 a2 = __shfl((int)w0, srcA + 16), b2 = __shfl((int)w2, srcA + 16);
      u32 a3 = __shfl((int)w1, srcA + 16), b3 = __shfl((int)w3, srcA + 16);
      pt0.w[0] = hi ? b0 : a0; pt0.w[1] = hi ? b1 : a1;
      pt0.w[2] = hi ? b2 : a2; pt0.w[3] = hi ? b3 : a3;
    }
    {
      u32 w0 = (u32)f2bf(p1[0]) | ((u32)f2bf(p1[1]) << 16);
      u32 w1 = (u32)f2bf(p1[2]) | ((u32)f2bf(p1[3]) << 16);
      u32 w2 = (u32)f2bf(p1[4]) | ((u32)f2bf(p1[5]) << 16);
      u32 w3 = (u32)f2bf(p1[6]) | ((u32)f2bf(p1[7]) << 16);
      u32 a0 = __shfl((int)w0, srcA),      b0 = __shfl((int)w2, srcA);
      u32 a1 = __shfl((int)w1, srcA),      b1 = __shfl((int)w3, srcA);
      u32 a2 = __shfl((int)w0, srcA + 16), b2 = __shfl((int)w2, srcA + 16);
      u32 a3 = __shfl((int)w1, srcA + 16), b3 = __shfl((int)w3, srcA + 16);
      pt1.w[0] = hi ? b0 : a0; pt1.w[1] = hi ? b1 : a1;
      pt1.w[2] = hi ? b2 : a2; pt1.w[3] = hi ? b3 : a3;
    }

    const u16* Vc = &Vs[cur][0];
    __builtin_amdgcn_s_setprio(1);
#pragma unroll
    for (int dt = 0; dt < 12; dt++) {
      bfx8 vf = *(const bfx8*)(Vc + dt * 512 + q15 * 32 + vsw * 8);
      acc[0][dt] = MFMA_BF16(vf, pt0.v, acc[0][dt]);
      acc[1][dt] = MFMA_BF16(vf, pt1.v, acc[1][dt]);
    }
    __builtin_amdgcn_s_setprio(0);

    // drain stores+stage for barrier correctness; copy loads stay in flight
    asm volatile("s_waitcnt vmcnt(3)" ::: "memory");
    __builtin_amdgcn_s_barrier();
    cur ^= 1;
  }

  // final copy slice (compiler inserts the load wait; loads are an iter old)
  {
    const size_t pb = (size_t)63 * 131072ull + cgid;
    __builtin_nontemporal_store(cr0, &cdst[pb]);
    __builtin_nontemporal_store(cr1, &cdst[pb + CSLAB]);
    __builtin_nontemporal_store(cr2, &cdst[pb + 2 * CSLAB]);
  }

  // deferred cross-lane l reduction
  l0 += __shfl_xor(l0, 16); l0 += __shfl_xor(l0, 32);
  l1 += __shfl_xor(l1, 16); l1 += __shfl_xor(l1, 32);

  float li0 = 1.f / l0, li1 = 1.f / l1;
  u16* ob = attnO + ((size_t)(b * 2048 + q0 + q15)) * 1536 + h * 192;
#pragma unroll
  for (int dt = 0; dt < 12; dt++) {
    u16x4 o0, o1;
#pragma unroll
    for (int j = 0; j < 4; j++) {
      o0[j] = f2bf(acc[0][dt][j] * li0);
      o1[j] = f2bf(acc[1][dt][j] * li1);
    }
    *(u16x4*)(ob + dt * 16 + g * 4) = o0;
    *(u16x4*)(ob + (size_t)16 * 1536 + dt * 16 + g * 4) = o1;
  }
}

// ---------------------------------------------------------------------------
extern "C" void kernel_launch(void* const* d_in, const int* in_sizes, int n_in,
                              void* d_out, int out_size, void* d_ws, size_t ws_size,
                              hipStream_t stream)
{
  const float* values0 = (const float*)d_in[0];
  const float* coords0 = (const float*)d_in[1];
  const float* values1 = (const float*)d_in[2];
  const float* coords1 = (const float*)d_in[3];
  const float* w_qkv   = (const float*)d_in[4];
  const float* qnorm_w = (const float*)d_in[5];
  const float* knorm_w = (const float*)d_in[6];
  const float* w_coords= (const float*)d_in[7];
  const float* cnorm_w = (const float*)d_in[8];
  const float* relw    = (const float*)d_in[9];
  const float* out_w   = (const float*)d_in[10];
  const float* out_b   = (const float*)d_in[11];
  float* out = (float*)d_out;
  (void)in_sizes; (void)n_in; (void)out_size; (void)ws_size;

  char* ws = (char*)d_ws;
  u16* qpack   = (u16*)(ws);                      // 50,331,648 B
  u16* kpack   = (u16*)(ws + 50331648ull);        // 50,331,648 B
  u16* vT      = (u16*)(ws + 100663296ull);       // 25,165,824 B
  u16* attnO   = (u16*)(ws + 125829120ull);       // 25,165,824 B
  u16* av      = (u16*)(ws + 150994944ull);       // 12,582,912 B
  u16* ac      = (u16*)(ws + 163577856ull);       //  2,097,152 B
  u16* wqkvT   = (u16*)(ws + 165675008ull);       //  7,077,888 B
  u16* wcoordT = (u16*)(ws + 172752896ull);       //    786,432 B
  u16* outwT   = (u16*)(ws + 173539328ull);       //  2,359,296 B

  wtrans_kernel<<<dim3(144, 24), dim3(32, 8), 0, stream>>>(w_qkv, wqkvT, 768, 4608);
  wtrans_kernel<<<dim3(96, 4),   dim3(32, 8), 0, stream>>>(w_coords, wcoordT, 128, 3072);
  wtrans_kernel<<<dim3(24, 48),  dim3(32, 8), 0, stream>>>(out_w, outwT, 1536, 768);
  gather_kernel<<<8192, 192, 0, stream>>>(values0, coords0, values1, coords1, av, ac);

  // qkv = av @ w_qkv : M=8192 N=4608 K=768, scatter into qpack/kpack/vT
  gemm128<2><<<dim3(36, 64), 256, 0, stream>>>(av, wqkvT, 768, 768, 768,
                                               qpack, kpack, vT, nullptr, nullptr);
  // coords = ac @ w_coords : M=8192 N=3072 K=128, scatter into coord halves
  gemm128<0><<<dim3(24, 64), 256, 0, stream>>>(ac, wcoordT, 128, 128, 128,
                                               qpack, kpack, nullptr, nullptr, nullptr);

  rms_all_kernel<<<8192, 192, 0, stream>>>(qpack, kpack, qnorm_w, knorm_w, cnorm_w, relw);

  // attention + fused values->out base copy (replaces the two hipMemcpyAsync)
  attn_kernel<<<512, 256, 0, stream>>>(qpack, kpack, vT, attnO,
                                       values0, values1, out);

  // out_proj + scatter-add: M=8192 N=768 K=1536, 64x128 tile (768 blocks)
  gemm_out64<<<dim3(6, 128), 256, 0, stream>>>(attnO, outwT, out, out_b);
}

// Round 15
// 484.090 us; speedup vs baseline: 1.0498x; 1.0255x over previous
//
#include <hip/hip_runtime.h>

typedef unsigned short u16;
typedef unsigned int u32;
typedef float f32x4 __attribute__((ext_vector_type(4)));
typedef short bfx8 __attribute__((ext_vector_type(8)));   // 8 bf16 held as shorts
typedef u16 u16x8 __attribute__((ext_vector_type(8)));
typedef u16 u16x4 __attribute__((ext_vector_type(4)));

#define MFMA_BF16(a,b,c) __builtin_amdgcn_mfma_f32_16x16x32_bf16((a),(b),(c),0,0,0)
#define GL16(src, dst) __builtin_amdgcn_global_load_lds( \
    (const __attribute__((address_space(1))) u32*)(src), \
    (__attribute__((address_space(3))) u32*)(dst), 16, 0, 0)

__device__ __forceinline__ u16 f2bf(float f) {
  unsigned u = __float_as_uint(f);
  u += 0x7fffu + ((u >> 16) & 1u);          // round to nearest even
  return (u16)(u >> 16);
}
__device__ __forceinline__ float bf2f(u16 h) {
  return __uint_as_float((unsigned)h << 16);
}

// XCD-chunked block remap (T1): requires nwg % 8 == 0 (bijective).
__device__ __forceinline__ void xcd_remap(int& bx, int& by) {
  int gx = gridDim.x, nwg = gx * gridDim.y;
  int id = by * gx + bx;
  int swz = (id & 7) * (nwg >> 3) + (id >> 3);
  bx = swz % gx; by = swz / gx;
}

#define SCALE_ATTN 0.07216878364870323f    // 192^-0.5

// ---------------------------------------------------------------------------
// Weight transpose: in (K x N) f32 row-major -> out (N x K) bf16 row-major
// ---------------------------------------------------------------------------
__global__ __launch_bounds__(256) void wtrans_kernel(
    const float* __restrict__ in, u16* __restrict__ out, int K, int N)
{
  __shared__ float tile[32][33];
  int n0 = blockIdx.x * 32, k0 = blockIdx.y * 32;
  int tx = threadIdx.x, ty = threadIdx.y;   // block (32,8)
#pragma unroll
  for (int j = 0; j < 32; j += 8)
    tile[ty + j][tx] = in[(size_t)(k0 + ty + j) * N + n0 + tx];
  __syncthreads();
#pragma unroll
  for (int j = 0; j < 32; j += 8)
    out[(size_t)(n0 + ty + j) * K + k0 + tx] = f2bf(tile[tx][ty + j]);
}

// ---------------------------------------------------------------------------
// Gather anchors (192 threads, 3 waves all active)
// ---------------------------------------------------------------------------
__global__ __launch_bounds__(192) void gather_kernel(
    const float* __restrict__ v0, const float* __restrict__ c0,
    const float* __restrict__ v1, const float* __restrict__ c1,
    u16* __restrict__ av, u16* __restrict__ ac)
{
  int t = blockIdx.x;
  int b = t >> 11, n = t & 2047, s = n >> 10, a = n & 1023, rr = a >> 5, cc = a & 31;
  size_t pix = ((size_t)b * 128 + (1 + 4 * rr)) * 128 + (1 + 4 * cc);
  const float4* vs = (const float4*)((s ? v1 : v0) + pix * 768);
  const float4* cs = (const float4*)((s ? c1 : c0) + pix * 128);
  int tid = threadIdx.x;                    // 0..191, all active on v
  {
    float4 f = vs[tid];
    u16x4 o = { f2bf(f.x), f2bf(f.y), f2bf(f.z), f2bf(f.w) };
    *(u16x4*)(av + (size_t)t * 768 + tid * 4) = o;
  }
  if (tid < 32) {
    float4 f = cs[tid];
    u16x4 o = { f2bf(f.x), f2bf(f.y), f2bf(f.z), f2bf(f.w) };
    *(u16x4*)(ac + (size_t)t * 128 + tid * 4) = o;
  }
}

// ---------------------------------------------------------------------------
// m97-structure GEMM (XCD-chunked). EPILOG 0: coords. EPILOG 2: qkv.
// ---------------------------------------------------------------------------
template<int EPILOG>
__global__ __launch_bounds__(256) void gemm128(
    const u16* __restrict__ A, const u16* __restrict__ Bt,
    int K, int lda, int ldb,
    u16* __restrict__ qp, u16* __restrict__ kp, u16* __restrict__ vT,
    float* __restrict__ outAdd, const float* __restrict__ bias)
{
  __shared__ u16 As[128 * 32];
  __shared__ u16 Bs[128 * 32];
  const int tid = threadIdx.x;
  const int wid = tid >> 6, lane = tid & 63;
  const int g = lane >> 4, q15 = lane & 15;
  const int wm = wid >> 1, wn = wid & 1;
  int bx = blockIdx.x, by = blockIdx.y;
  xcd_remap(bx, by);
  const int m0 = by * 128, n0 = bx * 128;

  const u16* ga = A + (size_t)(m0 + (tid >> 2)) * lda + (tid & 3) * 8;
  const u16* gb = Bt + (size_t)(n0 + (tid >> 2)) * ldb + (tid & 3) * 8;
  u16* lA0 = &As[tid * 8]; u16* lA1 = &As[2048 + tid * 8];
  u16* lB0 = &Bs[tid * 8]; u16* lB1 = &Bs[2048 + tid * 8];
  const size_t a64 = (size_t)64 * lda, b64 = (size_t)64 * ldb;

  const f32x4 zero = {0.f, 0.f, 0.f, 0.f};
  f32x4 acc[4][4];
#pragma unroll
  for (int i = 0; i < 4; i++)
#pragma unroll
    for (int j = 0; j < 4; j++) acc[i][j] = zero;

  for (int kk = 0; kk < K; kk += 32) {
    GL16(ga + kk, lA0);
    GL16(ga + kk + a64, lA1);
    GL16(gb + kk, lB0);
    GL16(gb + kk + b64, lB1);
    __syncthreads();
    bfx8 af[4], bf[4];
#pragma unroll
    for (int mt = 0; mt < 4; mt++)
      af[mt] = *(const bfx8*)&As[(wm * 64 + mt * 16 + q15) * 32 + g * 8];
#pragma unroll
    for (int nt = 0; nt < 4; nt++)
      bf[nt] = *(const bfx8*)&Bs[(wn * 64 + nt * 16 + q15) * 32 + g * 8];
#pragma unroll
    for (int mt = 0; mt < 4; mt++)
#pragma unroll
      for (int nt = 0; nt < 4; nt++)
        acc[mt][nt] = MFMA_BF16(af[mt], bf[nt], acc[mt][nt]);
    __syncthreads();
  }

#pragma unroll
  for (int mt = 0; mt < 4; mt++) {
#pragma unroll
    for (int nt = 0; nt < 4; nt++) {
      const int tt = m0 + wm * 64 + mt * 16 + g * 4;      // token base (+j)
      const int c = n0 + wn * 64 + nt * 16 + q15;         // output column
      f32x4 v = acc[mt][nt];
      if (EPILOG == 0) {
        // coords: c<1536 -> qc, else kc
        int isK = c >= 1536;
        int ck = isK ? c - 1536 : c;
        int hh = ck / 192, dd = ck - hh * 192;
#pragma unroll
        for (int j = 0; j < 4; j++) {
          int t = tt + j, b = t >> 11, n = t & 2047;
          size_t ro = ((size_t)(b * 8 + hh) * 2048 + n) * 384;
          u16 val = f2bf(v[j]);
          if (!isK) qp[ro + 192 + dd] = val;
          else      kp[ro + (size_t)((((24 + (dd >> 3)) ^ (n & 7)) << 3) + (dd & 7))] = val;
        }
      } else {
        // qkv: c<1536 q | <3072 k | else v
        if (c < 1536) {
          int hh = c / 192, dd = c - hh * 192;
#pragma unroll
          for (int j = 0; j < 4; j++) {
            int t = tt + j, b = t >> 11, n = t & 2047;
            size_t ro = ((size_t)(b * 8 + hh) * 2048 + n) * 384;
            qp[ro + dd] = f2bf(v[j]);
          }
        } else if (c < 3072) {
          int ck = c - 1536;
          int hh = ck / 192, dd = ck - hh * 192;
          int chunk = dd >> 3, e = dd & 7;
#pragma unroll
          for (int j = 0; j < 4; j++) {
            int t = tt + j, b = t >> 11, n = t & 2047;
            size_t ro = ((size_t)(b * 8 + hh) * 2048 + n) * 384;
            kp[ro + (size_t)(((chunk ^ (n & 7)) << 3) + e)] = f2bf(v[j]);
          }
        } else {
          int cv = c - 3072;
          int hh = cv / 192, dv = cv - hh * 192;
          int t0 = tt, b = t0 >> 11, n = t0 & 2047;
          u16x4 o = { f2bf(v[0]), f2bf(v[1]), f2bf(v[2]), f2bf(v[3]) };
          *(u16x4*)(vT + ((size_t)(b * 8 + hh) * 192 + dv) * 2048 + n) = o;
        }
      }
    }
  }
}

// ---------------------------------------------------------------------------
// Out-proj GEMM, 64x128 tile (768 blocks, 3/CU) -- confirmed -14 us.
// ---------------------------------------------------------------------------
__global__ __launch_bounds__(256) void gemm_out64(
    const u16* __restrict__ A, const u16* __restrict__ Bt,
    float* __restrict__ outAdd, const float* __restrict__ bias)
{
  __shared__ u16 As[64 * 32];
  __shared__ u16 Bs[128 * 32];
  const int K = 1536;
  const int tid = threadIdx.x;
  const int wid = tid >> 6, lane = tid & 63;
  const int g = lane >> 4, q15 = lane & 15;
  const int wm = wid >> 1, wn = wid & 1;
  int bx = blockIdx.x, by = blockIdx.y;
  xcd_remap(bx, by);
  const int m0 = by * 64, n0 = bx * 128;

  const u16* ga = A + (size_t)(m0 + (tid >> 2)) * K + (tid & 3) * 8;
  const u16* gb = Bt + (size_t)(n0 + (tid >> 2)) * K + (tid & 3) * 8;
  u16* lA0 = &As[tid * 8];
  u16* lB0 = &Bs[tid * 8]; u16* lB1 = &Bs[2048 + tid * 8];
  const size_t b64 = (size_t)64 * K;

  const f32x4 zero = {0.f, 0.f, 0.f, 0.f};
  f32x4 acc[2][4];
#pragma unroll
  for (int i = 0; i < 2; i++)
#pragma unroll
    for (int j = 0; j < 4; j++) acc[i][j] = zero;

  for (int kk = 0; kk < K; kk += 32) {
    GL16(ga + kk, lA0);
    GL16(gb + kk, lB0);
    GL16(gb + kk + b64, lB1);
    __syncthreads();
    bfx8 af[2], bf[4];
#pragma unroll
    for (int mt = 0; mt < 2; mt++)
      af[mt] = *(const bfx8*)&As[(wm * 32 + mt * 16 + q15) * 32 + g * 8];
#pragma unroll
    for (int nt = 0; nt < 4; nt++)
      bf[nt] = *(const bfx8*)&Bs[(wn * 64 + nt * 16 + q15) * 32 + g * 8];
#pragma unroll
    for (int mt = 0; mt < 2; mt++)
#pragma unroll
      for (int nt = 0; nt < 4; nt++)
        acc[mt][nt] = MFMA_BF16(af[mt], bf[nt], acc[mt][nt]);
    __syncthreads();
  }

#pragma unroll
  for (int mt = 0; mt < 2; mt++) {
#pragma unroll
    for (int nt = 0; nt < 4; nt++) {
      const int tt = m0 + wm * 32 + mt * 16 + g * 4;
      const int c = n0 + wn * 64 + nt * 16 + q15;
      f32x4 v = acc[mt][nt];
      float bb = bias[c];
#pragma unroll
      for (int j = 0; j < 4; j++) {
        int t = tt + j, b = t >> 11, n = t & 2047;
        int s = n >> 10, a = n & 1023, rr = a >> 5, cc2 = a & 31;
        size_t orow = (size_t)(s * 4 + b) * 16384 + (size_t)(1 + 4 * rr) * 128 + (1 + 4 * cc2);
        outAdd[orow * 768 + c] += v[j] + bb;
      }
    }
  }
}

// ---------------------------------------------------------------------------
// Fused RMSNorm (192-thread blocks, 3 waves all active).
// ---------------------------------------------------------------------------
__global__ __launch_bounds__(192) void rms_all_kernel(
    u16* __restrict__ qpack, u16* __restrict__ kpack,
    const float* __restrict__ qnw, const float* __restrict__ knw,
    const float* __restrict__ cnw, const float* __restrict__ relw)
{
  __shared__ float red[3][3];
  int t = blockIdx.x, tid = threadIdx.x;   // tid 0..191, all active
  int b = t >> 11, n = t & 2047;
  float sqv = 0.f, skv = 0.f, sc = 0.f;
  u16x8 uqv, ukv, uqc, ukc;
  int h = tid / 24, c = tid % 24;
  size_t ro = ((size_t)(b * 8 + h) * 2048 + n) * 384;
  uqv = *(const u16x8*)(qpack + ro + c * 8);
  ukv = *(const u16x8*)(kpack + ro + ((c ^ (n & 7)) * 8));
  uqc = *(const u16x8*)(qpack + ro + 192 + c * 8);
  ukc = *(const u16x8*)(kpack + ro + (((24 + c) ^ (n & 7)) * 8));
#pragma unroll
  for (int e = 0; e < 8; e++) {
    float a = bf2f(uqv[e]); sqv += a * a;
    float d = bf2f(ukv[e]); skv += d * d;
    float x = bf2f(uqc[e]); sc += x * x;
    float y = bf2f(ukc[e]); sc += y * y;
  }
#pragma unroll
  for (int o = 32; o >= 1; o >>= 1) {
    sqv += __shfl_xor(sqv, o); skv += __shfl_xor(skv, o); sc += __shfl_xor(sc, o);
  }
  int wv = tid >> 6;
  if ((tid & 63) == 0) { red[0][wv] = sqv; red[1][wv] = skv; red[2][wv] = sc; }
  __syncthreads();
  sqv = red[0][0] + red[0][1] + red[0][2];
  skv = red[1][0] + red[1][1] + red[1][2];
  sc  = red[2][0] + red[2][1] + red[2][2];
  float fqv = rsqrtf(sqv * (1.f / 1536.f) + 1e-6f) * SCALE_ATTN;
  float fkv = rsqrtf(skv * (1.f / 1536.f) + 1e-6f);
  float fc  = rsqrtf(sc * (1.f / 3072.f) + 1e-6f);
  float fqc = fc * SCALE_ATTN * relw[0];
  u16x8 o0, o1, o2, o3;
#pragma unroll
  for (int e = 0; e < 8; e++) {
    int col = tid * 8 + e;
    o0[e] = f2bf(bf2f(uqv[e]) * fqv * qnw[col]);
    o1[e] = f2bf(bf2f(ukv[e]) * fkv * knw[col]);
    o2[e] = f2bf(bf2f(uqc[e]) * fqc * cnw[col]);
    o3[e] = f2bf(bf2f(ukc[e]) * fc  * cnw[1536 + col]);
  }
  *(u16x8*)(qpack + ro + c * 8) = o0;
  *(u16x8*)(kpack + ro + ((c ^ (n & 7)) * 8)) = o1;
  *(u16x8*)(qpack + ro + 192 + c * 8) = o2;
  *(u16x8*)(kpack + ro + (((24 + c) ^ (n & 7)) * 8)) = o3;
}

// ---------------------------------------------------------------------------
// Flash attention (round-3 proven schedule -- correct under FIFO vmcnt
// retirement):
//   iter t:  store slice t-1 (nt)  ->  stage K/V t+1  ->  load slice t (nt)
//            -> compute  ->  s_waitcnt vmcnt(3)  ->  raw s_barrier
// ---------------------------------------------------------------------------
__global__ __launch_bounds__(256, 2) void attn_kernel(
    const u16* __restrict__ qpack, const u16* __restrict__ kpack,
    const u16* __restrict__ vT, u16* __restrict__ attnO,
    const float* __restrict__ cpy_v0, const float* __restrict__ cpy_v1,
    float* __restrict__ cpy_out)
{
  __shared__ u16 Ks[2][32 * 384];   // 24 KB each, pre-swizzled content
  __shared__ u16 Vs[2][192 * 32];   // 12 KB each, source-swizzled staging

  const int tid = threadIdx.x;
  const int wid = tid >> 6, lane = tid & 63;
  const int g = lane >> 4, q15 = lane & 15;
  const int bid = blockIdx.x;
  const int bh = (bid & 7) * 4 + ((bid >> 3) >> 4);   // XCD-chunked
  const int q0 = ((bid >> 3) & 15) * 128 + wid * 32;
  const int b = bh >> 3, h = bh & 7;
  const int sw = q15 & 7;
  const int vsw = g ^ (q15 & 3);
  const bool hi = g >= 2;
  const int srcA = q15 + ((g & 1) << 5);

  // fused-copy pointers: 512 blk x 256 thr x 64 iter x 3 = 25,165,824 f32x4
  const f32x4* cs0 = (const f32x4*)cpy_v0;
  const f32x4* cs1 = (const f32x4*)cpy_v1;
  f32x4* cdst = (f32x4*)cpy_out;
  const size_t cgid = (size_t)bid * 256 + tid;
  const size_t CHALF = 12582912ull;          // f32x4 per half
  const size_t CSLAB = 8388608ull;           // 64 iters * 131072 threads

  bfx8 qf[2][12];
  {
    const u16* qb = qpack + ((size_t)bh * 2048 + q0 + q15) * 384 + g * 8;
#pragma unroll
    for (int s = 0; s < 2; s++)
#pragma unroll
      for (int c = 0; c < 12; c++)
        qf[s][c] = *(const bfx8*)(qb + s * 16 * 384 + c * 32);
  }

  const f32x4 zero = {0.f, 0.f, 0.f, 0.f};
  f32x4 acc[2][12];
#pragma unroll
  for (int s = 0; s < 2; s++)
#pragma unroll
    for (int i = 0; i < 12; i++) acc[s][i] = zero;
  float m0 = -3e30f, m1 = -3e30f, l0 = 0.f, l1 = 0.f;

  const char* kg = (const char*)(kpack + (size_t)bh * 2048 * 384);
  const char* vg = (const char*)(vT + (size_t)bh * 192 * 2048);

  auto stage = [&](int buf, int kb) {
    const char* ks = kg + (size_t)kb * 768;
#pragma unroll
    for (int j = 0; j < 6; j++) {
      int off = j * 4096 + tid * 16;
      GL16(ks + off, (char*)&Ks[buf][0] + off);
    }
    const char* vsrc = vg + (size_t)kb * 2;
#pragma unroll
    for (int j = 0; j < 3; j++) {
      int off = j * 4096 + tid * 16;
      int row = off >> 6;
      int cc = (tid & 3) ^ (row & 3);
      GL16(vsrc + (size_t)row * 4096 + cc * 16, (char*)&Vs[buf][0] + off);
    }
  };

  stage(0, 0);
  asm volatile("s_waitcnt vmcnt(0)" ::: "memory");
  __builtin_amdgcn_s_barrier();

  int cur = 0;
  f32x4 cr0, cr1, cr2;
  for (int t = 0; t < 64; t++) {
    // 1. store slice t-1 (data loaded a full iteration ago -> wait is free)
    if (t > 0) {
      const size_t pb = (size_t)(t - 1) * 131072ull + cgid;
      __builtin_nontemporal_store(cr0, &cdst[pb]);
      __builtin_nontemporal_store(cr1, &cdst[pb + CSLAB]);
      __builtin_nontemporal_store(cr2, &cdst[pb + 2 * CSLAB]);
    }
    // 2. stage next K/V tile (9 global_load_lds)
    if (t < 63) stage(cur ^ 1, (t + 1) * 32);
    // 3. issue copy loads for slice t (3 newest vmem ops -> excluded by vmcnt(3))
    {
      const size_t i0 = (size_t)t * 131072ull + cgid;
      const size_t i1 = i0 + CSLAB, i2 = i0 + 2 * CSLAB;
      cr0 = __builtin_nontemporal_load(&cs0[i0]);                 // slab0 in v0
      cr1 = (i1 < CHALF) ? __builtin_nontemporal_load(&cs0[i1])
                         : __builtin_nontemporal_load(&cs1[i1 - CHALF]);
      cr2 = __builtin_nontemporal_load(&cs1[i2 - CHALF]);         // slab2 in v1
    }

    f32x4 s00 = zero, s01 = zero, s10 = zero, s11 = zero;
    const u16* Kc = &Ks[cur][0];
    __builtin_amdgcn_s_setprio(1);
#pragma unroll
    for (int c = 0; c < 12; c++) {
      int ch = ((((c << 2) + g) ^ sw) << 3);
      bfx8 k0 = *(const bfx8*)(Kc + q15 * 384 + ch);
      bfx8 k1 = *(const bfx8*)(Kc + (q15 + 16) * 384 + ch);
      s00 = MFMA_BF16(k0, qf[0][c], s00);
      s01 = MFMA_BF16(k0, qf[1][c], s01);
      s10 = MFMA_BF16(k1, qf[0][c], s10);
      s11 = MFMA_BF16(k1, qf[1][c], s11);
    }
    __builtin_amdgcn_s_setprio(0);

    // per-lane partial max only; full cross-lane reduce deferred into the
    // rarely-taken rescale branch (__any over partials == __any over max)
    float bm0 = fmaxf(fmaxf(fmaxf(s00[0], s00[1]), fmaxf(s00[2], s00[3])),
                      fmaxf(fmaxf(s10[0], s10[1]), fmaxf(s10[2], s10[3])));
    float bm1 = fmaxf(fmaxf(fmaxf(s01[0], s01[1]), fmaxf(s01[2], s01[3])),
                      fmaxf(fmaxf(s11[0], s11[1]), fmaxf(s11[2], s11[3])));

    if (__any((bm0 > m0 + 8.f) | (bm1 > m1 + 8.f))) {   // defer-max (T13)
      bm0 = fmaxf(bm0, __shfl_xor(bm0, 16)); bm0 = fmaxf(bm0, __shfl_xor(bm0, 32));
      bm1 = fmaxf(bm1, __shfl_xor(bm1, 16)); bm1 = fmaxf(bm1, __shfl_xor(bm1, 32));
      float n0 = fmaxf(m0, bm0), n1 = fmaxf(m1, bm1);
      float c0 = __expf(m0 - n0), c1 = __expf(m1 - n1);
      l0 *= c0; l1 *= c1;
#pragma unroll
      for (int i = 0; i < 12; i++) {
#pragma unroll
        for (int j = 0; j < 4; j++) { acc[0][i][j] *= c0; acc[1][i][j] *= c1; }
      }
      m0 = n0; m1 = n1;
    }

    float p0[8], p1[8];
    float rs0 = 0.f, rs1 = 0.f;
#pragma unroll
    for (int j = 0; j < 4; j++) {
      p0[j]     = __expf(s00[j] - m0);
      p0[4 + j] = __expf(s10[j] - m0);
      p1[j]     = __expf(s01[j] - m1);
      p1[4 + j] = __expf(s11[j] - m1);
      rs0 += p0[j] + p0[4 + j];
      rs1 += p1[j] + p1[4 + j];
    }
    // per-lane partial l; cross-lane reduce deferred to after the loop
    l0 += rs0; l1 += rs1;

    union { bfx8 v; u32 w[4]; } pt0, pt1;
    {
      u32 w0 = (u32)f2bf(p0[0]) | ((u32)f2bf(p0[1]) << 16);
      u32 w1 = (u32)f2bf(p0[2]) | ((u32)f2bf(p0[3]) << 16);
      u32 w2 = (u32)f2bf(p0[4]) | ((u32)f2bf(p0[5]) << 16);
      u32 w3 = (u32)f2bf(p0[6]) | ((u32)f2bf(p0[7]) << 16);
      u32 a0 = __shfl((int)w0, srcA),      b0 = __shfl((int)w2, srcA);
      u32 a1 = __shfl((int)w1, srcA),      b1 = __shfl((int)w3, srcA);
      u32 a2 = __shfl((int)w0, srcA + 16), b2 = __shfl((int)w2, srcA + 16);
      u32 a3 = __shfl((int)w1, srcA + 16), b3 = __shfl((int)w3, srcA + 16);
      pt0.w[0] = hi ? b0 : a0; pt0.w[1] = hi ? b1 : a1;
      pt0.w[2] = hi ? b2 : a2; pt0.w[3] = hi ? b3 : a3;
    }
    {
      u32 w0 = (u32)f2bf(p1[0]) | ((u32)f2bf(p1[1]) << 16);
      u32 w1 = (u32)f2bf(p1[2]) | ((u32)f2bf(p1[3]) << 16);
      u32 w2 = (u32)f2bf(p1[4]) | ((u32)f2bf(p1[5]) << 16);
      u32 w3 = (u32)f2bf(p1[6]) | ((u32)f2bf(p1[7]) << 16);
      u32 a0 = __shfl((int)w0, srcA),      b0 = __shfl((int)w2, srcA);
      u32 a1 = __shfl((int)w1, srcA),      b1 = __shfl((int)w3, srcA);
      u32 a2 = __shfl((int)w0, srcA + 16), b2 = __shfl((int)w2, srcA + 16);
      u32 a3 = __shfl((int)w1, srcA + 16), b3 = __shfl((int)w3, srcA + 16);
      pt1.w[0] = hi ? b0 : a0; pt1.w[1] = hi ? b1 : a1;
      pt1.w[2] = hi ? b2 : a2; pt1.w[3] = hi ? b3 : a3;
    }

    const u16* Vc = &Vs[cur][0];
    __builtin_amdgcn_s_setprio(1);
#pragma unroll
    for (int dt = 0; dt < 12; dt++) {
      bfx8 vf = *(const bfx8*)(Vc + dt * 512 + q15 * 32 + vsw * 8);
      acc[0][dt] = MFMA_BF16(vf, pt0.v, acc[0][dt]);
      acc[1][dt] = MFMA_BF16(vf, pt1.v, acc[1][dt]);
    }
    __builtin_amdgcn_s_setprio(0);

    // drain stores+stage for barrier correctness; copy loads stay in flight
    asm volatile("s_waitcnt vmcnt(3)" ::: "memory");
    __builtin_amdgcn_s_barrier();
    cur ^= 1;
  }

  // final copy slice (compiler inserts the load wait; loads are an iter old)
  {
    const size_t pb = (size_t)63 * 131072ull + cgid;
    __builtin_nontemporal_store(cr0, &cdst[pb]);
    __builtin_nontemporal_store(cr1, &cdst[pb + CSLAB]);
    __builtin_nontemporal_store(cr2, &cdst[pb + 2 * CSLAB]);
  }

  // deferred cross-lane l reduction
  l0 += __shfl_xor(l0, 16); l0 += __shfl_xor(l0, 32);
  l1 += __shfl_xor(l1, 16); l1 += __shfl_xor(l1, 32);

  float li0 = 1.f / l0, li1 = 1.f / l1;
  u16* ob = attnO + ((size_t)(b * 2048 + q0 + q15)) * 1536 + h * 192;
#pragma unroll
  for (int dt = 0; dt < 12; dt++) {
    u16x4 o0, o1;
#pragma unroll
    for (int j = 0; j < 4; j++) {
      o0[j] = f2bf(acc[0][dt][j] * li0);
      o1[j] = f2bf(acc[1][dt][j] * li1);
    }
    *(u16x4*)(ob + dt * 16 + g * 4) = o0;
    *(u16x4*)(ob + (size_t)16 * 1536 + dt * 16 + g * 4) = o1;
  }
}

// ---------------------------------------------------------------------------
extern "C" void kernel_launch(void* const* d_in, const int* in_sizes, int n_in,
                              void* d_out, int out_size, void* d_ws, size_t ws_size,
                              hipStream_t stream)
{
  const float* values0 = (const float*)d_in[0];
  const float* coords0 = (const float*)d_in[1];
  const float* values1 = (const float*)d_in[2];
  const float* coords1 = (const float*)d_in[3];
  const float* w_qkv   = (const float*)d_in[4];
  const float* qnorm_w = (const float*)d_in[5];
  const float* knorm_w = (const float*)d_in[6];
  const float* w_coords= (const float*)d_in[7];
  const float* cnorm_w = (const float*)d_in[8];
  const float* relw    = (const float*)d_in[9];
  const float* out_w   = (const float*)d_in[10];
  const float* out_b   = (const float*)d_in[11];
  float* out = (float*)d_out;
  (void)in_sizes; (void)n_in; (void)out_size; (void)ws_size;

  char* ws = (char*)d_ws;
  u16* qpack   = (u16*)(ws);                      // 50,331,648 B
  u16* kpack   = (u16*)(ws + 50331648ull);        // 50,331,648 B
  u16* vT      = (u16*)(ws + 100663296ull);       // 25,165,824 B
  u16* attnO   = (u16*)(ws + 125829120ull);       // 25,165,824 B
  u16* av      = (u16*)(ws + 150994944ull);       // 12,582,912 B
  u16* ac      = (u16*)(ws + 163577856ull);       //  2,097,152 B
  u16* wqkvT   = (u16*)(ws + 165675008ull);       //  7,077,888 B
  u16* wcoordT = (u16*)(ws + 172752896ull);       //    786,432 B
  u16* outwT   = (u16*)(ws + 173539328ull);       //  2,359,296 B

  wtrans_kernel<<<dim3(144, 24), dim3(32, 8), 0, stream>>>(w_qkv, wqkvT, 768, 4608);
  wtrans_kernel<<<dim3(96, 4),   dim3(32, 8), 0, stream>>>(w_coords, wcoordT, 128, 3072);
  wtrans_kernel<<<dim3(24, 48),  dim3(32, 8), 0, stream>>>(out_w, outwT, 1536, 768);
  gather_kernel<<<8192, 192, 0, stream>>>(values0, coords0, values1, coords1, av, ac);

  // qkv = av @ w_qkv : M=8192 N=4608 K=768, scatter into qpack/kpack/vT
  gemm128<2><<<dim3(36, 64), 256, 0, stream>>>(av, wqkvT, 768, 768, 768,
                                               qpack, kpack, vT, nullptr, nullptr);
  // coords = ac @ w_coords : M=8192 N=3072 K=128, scatter into coord halves
  gemm128<0><<<dim3(24, 64), 256, 0, stream>>>(ac, wcoordT, 128, 128, 128,
                                               qpack, kpack, nullptr, nullptr, nullptr);

  rms_all_kernel<<<8192, 192, 0, stream>>>(qpack, kpack, qnorm_w, knorm_w, cnorm_w, relw);

  // attention + fused values->out base copy (replaces the two hipMemcpyAsync)
  attn_kernel<<<512, 256, 0, stream>>>(qpack, kpack, vT, attnO,
                                       values0, values1, out);

  // out_proj + scatter-add: M=8192 N=768 K=1536, 64x128 tile (768 blocks)
  gemm_out64<<<dim3(6, 128), 256, 0, stream>>>(attnO, outwT, out, out_b);
}